// Round 1
// baseline (450.970 us; speedup 1.0000x reference)
//
#include <hip/hip_runtime.h>
#include <hip/hip_bf16.h>

typedef unsigned short u16;
typedef unsigned int u32;
typedef __attribute__((ext_vector_type(8))) short bf16x8;
typedef __attribute__((ext_vector_type(4))) float f32x4;

#define T_TOK 8192
#define DIN 4096
#define DOUT 4096
#define N_SEQS 4
#define N_ADPT 8
#define MAXR 64
#define CACHE_LEN 512

__device__ __forceinline__ u16 f2bf(float f) {
    u32 u = __builtin_bit_cast(u32, f);
    u += 0x7fffu + ((u >> 16) & 1u);   // RNE
    return (u16)(u >> 16);
}

__device__ __forceinline__ void load_lds16(const u16* g, u16* l) {
    __builtin_amdgcn_global_load_lds(
        (const __attribute__((address_space(1))) u32*)g,
        (__attribute__((address_space(3))) u32*)l, 16, 0, 0);
}

// ---------------- fp32 -> bf16 convert (vectorized) ----------------
__global__ void cvt_kernel(const float* __restrict__ in, u16* __restrict__ out, int n4) {
    int i = blockIdx.x * blockDim.x + threadIdx.x;
    int stride = gridDim.x * blockDim.x;
    for (; i < n4; i += stride) {
        float4 v = reinterpret_cast<const float4*>(in)[i];
        ushort4 o;
        o.x = f2bf(v.x); o.y = f2bf(v.y); o.z = f2bf(v.z); o.w = f2bf(v.w);
        reinterpret_cast<ushort4*>(out)[i] = o;
    }
}

// ------------- build Bt[a][n][r] bf16 from b_cache via page table -------------
__global__ void build_bt(const float* __restrict__ b_cache, const int* __restrict__ rpt,
                         u16* __restrict__ Bt) {
    // id = (a*8 + rb)*DOUT + n ; thread handles 8 ranks rb*8..rb*8+7 for (a,n)
    int id = blockIdx.x * 256 + threadIdx.x;      // total 8*8*4096 = 262144
    int n  = id & (DOUT - 1);
    int rb = (id >> 12) & 7;
    int a  = id >> 15;
    union { u16 u[8]; uint4 v; } pack;
    #pragma unroll
    for (int j = 0; j < 8; ++j) {
        int r = rb * 8 + j;
        int page = rpt[a * MAXR + r];
        pack.u[j] = f2bf(b_cache[(long)page * DOUT + n]);
    }
    *reinterpret_cast<uint4*>(&Bt[((long)(a * DOUT + n)) * MAXR + rb * 8]) = pack.v;
}

// ------------- xa[t][r] = scale * (x[t] . A[page(adapter,r)]), masked -------------
__launch_bounds__(256)
__global__ void xa_kernel(const u16* __restrict__ xb, const u16* __restrict__ ab,
                          const int* __restrict__ b_start_loc,
                          const int* __restrict__ b_adapter_ids,
                          const float* __restrict__ b_scaling,
                          const int* __restrict__ rpt,
                          const int* __restrict__ ranks,
                          u16* __restrict__ xa) {
    int t0 = blockIdx.x * 128;
    int seg = 0;
    #pragma unroll
    for (int i = 1; i < N_SEQS; ++i) if (b_start_loc[i] <= t0) seg = i;
    int adapter = b_adapter_ids[seg];
    float scale = b_scaling[seg];
    int rank = ranks[adapter];

    __shared__ __attribute__((aligned(16))) u16 As[128 * 32];
    __shared__ __attribute__((aligned(16))) u16 Bs[64 * 32];

    int tid = threadIdx.x;
    int lane = tid & 63, wave = tid >> 6;
    int lr = lane & 15, lk = lane >> 4;

    int e0 = wave * 64 + lane;               // [0,256)
    int e1 = 256 + e0;                       // [256,512)
    int ra0 = e0 >> 2, ca0 = (e0 & 3) * 8;
    int ra1 = e1 >> 2, ca1 = (e1 & 3) * 8;
    const u16* gA0 = xb + (long)(t0 + ra0) * DIN + ca0;
    const u16* gA1 = xb + (long)(t0 + ra1) * DIN + ca1;
    int rB = ra0;                            // B-tile row (rank slot), fixed per thread
    int page = rpt[adapter * MAXR + rB];
    const u16* gB = ab + (long)page * DIN + ca0;

    f32x4 acc[2][4] = {};

    for (int k0 = 0; k0 < DIN; k0 += 32) {
        load_lds16(gA0 + k0, As + wave * 512);
        load_lds16(gA1 + k0, As + 2048 + wave * 512);
        load_lds16(gB + k0,  Bs + wave * 512);
        asm volatile("s_waitcnt vmcnt(0)" ::: "memory");
        __syncthreads();
        bf16x8 af[2], bfr[4];
        #pragma unroll
        for (int m = 0; m < 2; ++m)
            af[m] = *(const bf16x8*)&As[(wave * 32 + m * 16 + lr) * 32 + lk * 8];
        #pragma unroll
        for (int n = 0; n < 4; ++n)
            bfr[n] = *(const bf16x8*)&Bs[(n * 16 + lr) * 32 + lk * 8];
        #pragma unroll
        for (int m = 0; m < 2; ++m)
            #pragma unroll
            for (int n = 0; n < 4; ++n)
                acc[m][n] = __builtin_amdgcn_mfma_f32_16x16x32_bf16(af[m], bfr[n], acc[m][n], 0, 0, 0);
        __syncthreads();
    }

    #pragma unroll
    for (int m = 0; m < 2; ++m) {
        int trow = t0 + wave * 32 + m * 16 + lk * 4;
        #pragma unroll
        for (int n = 0; n < 4; ++n) {
            int r = n * 16 + lr;
            #pragma unroll
            for (int j = 0; j < 4; ++j) {
                float v = (r < rank) ? acc[m][n][j] * scale : 0.0f;
                xa[(long)(trow + j) * MAXR + r] = f2bf(v);
            }
        }
    }
}

// ------------- main GEMM: out = x@W^T + bias + xa@Bt^T (lora fused as K-ext) -------------
__launch_bounds__(256)
__global__ void gemm_kernel(const u16* __restrict__ xb, const u16* __restrict__ wb,
                            const float* __restrict__ bias,
                            const u16* __restrict__ xa, const u16* __restrict__ Bt,
                            const int* __restrict__ b_start_loc,
                            const int* __restrict__ b_adapter_ids,
                            float* __restrict__ out) {
    const int NT = DOUT / 128;               // 32 col tiles
    int bid = blockIdx.x;
    int mt = bid / NT, nt = bid % NT;
    int brow = mt * 128, bcol = nt * 128;

    int seg = 0;
    #pragma unroll
    for (int i = 1; i < N_SEQS; ++i) if (b_start_loc[i] <= brow) seg = i;
    int adapter = b_adapter_ids[seg];

    __shared__ __attribute__((aligned(16))) u16 As[128 * 32];
    __shared__ __attribute__((aligned(16))) u16 Bs[128 * 32];

    int tid = threadIdx.x;
    int lane = tid & 63, wave = tid >> 6;
    int wm = wave >> 1, wn = wave & 1;       // 2x2 wave grid, 64x64 each
    int lr = lane & 15, lk = lane >> 4;

    int e0 = wave * 64 + lane;
    int e1 = 256 + e0;
    int ra0 = e0 >> 2, ca0 = (e0 & 3) * 8;
    int ra1 = e1 >> 2, ca1 = (e1 & 3) * 8;
    const u16* gA0 = xb + (long)(brow + ra0) * DIN + ca0;
    const u16* gA1 = xb + (long)(brow + ra1) * DIN + ca1;
    const u16* gB0 = wb + (long)(bcol + ra0) * DIN + ca0;
    const u16* gB1 = wb + (long)(bcol + ra1) * DIN + ca1;

    f32x4 acc[4][4] = {};

    for (int k0 = 0; k0 < DIN; k0 += 32) {
        load_lds16(gA0 + k0, As + wave * 512);
        load_lds16(gA1 + k0, As + 2048 + wave * 512);
        load_lds16(gB0 + k0, Bs + wave * 512);
        load_lds16(gB1 + k0, Bs + 2048 + wave * 512);
        asm volatile("s_waitcnt vmcnt(0)" ::: "memory");
        __syncthreads();
        bf16x8 af[4], bfr[4];
        #pragma unroll
        for (int m = 0; m < 4; ++m)
            af[m] = *(const bf16x8*)&As[(wm * 64 + m * 16 + lr) * 32 + lk * 8];
        #pragma unroll
        for (int n = 0; n < 4; ++n)
            bfr[n] = *(const bf16x8*)&Bs[(wn * 64 + n * 16 + lr) * 32 + lk * 8];
        #pragma unroll
        for (int m = 0; m < 4; ++m)
            #pragma unroll
            for (int n = 0; n < 4; ++n)
                acc[m][n] = __builtin_amdgcn_mfma_f32_16x16x32_bf16(af[m], bfr[n], acc[m][n], 0, 0, 0);
        __syncthreads();
    }

    // ---- LoRA K-extension: 2 steps of BK=32 over the rank dim ----
    const u16* gXa = xa + (long)brow * MAXR;
    const u16* gBt = Bt + ((long)adapter * DOUT + bcol) * MAXR;
    for (int r0 = 0; r0 < MAXR; r0 += 32) {
        load_lds16(gXa + (long)ra0 * MAXR + r0 + ca0, As + wave * 512);
        load_lds16(gXa + (long)ra1 * MAXR + r0 + ca1, As + 2048 + wave * 512);
        load_lds16(gBt + (long)ra0 * MAXR + r0 + ca0, Bs + wave * 512);
        load_lds16(gBt + (long)ra1 * MAXR + r0 + ca1, Bs + 2048 + wave * 512);
        asm volatile("s_waitcnt vmcnt(0)" ::: "memory");
        __syncthreads();
        bf16x8 af[4], bfr[4];
        #pragma unroll
        for (int m = 0; m < 4; ++m)
            af[m] = *(const bf16x8*)&As[(wm * 64 + m * 16 + lr) * 32 + lk * 8];
        #pragma unroll
        for (int n = 0; n < 4; ++n)
            bfr[n] = *(const bf16x8*)&Bs[(wn * 64 + n * 16 + lr) * 32 + lk * 8];
        #pragma unroll
        for (int m = 0; m < 4; ++m)
            #pragma unroll
            for (int n = 0; n < 4; ++n)
                acc[m][n] = __builtin_amdgcn_mfma_f32_16x16x32_bf16(af[m], bfr[n], acc[m][n], 0, 0, 0);
        __syncthreads();
    }

    // ---- epilogue: + bias, fp32 store ----
    #pragma unroll
    for (int m = 0; m < 4; ++m) {
        int orow = brow + wm * 64 + m * 16 + lk * 4;
        #pragma unroll
        for (int n = 0; n < 4; ++n) {
            int ocol = bcol + wn * 64 + n * 16 + lr;
            float bv = bias[ocol];
            #pragma unroll
            for (int j = 0; j < 4; ++j)
                out[(long)(orow + j) * DOUT + ocol] = acc[m][n][j] + bv;
        }
    }
}

extern "C" void kernel_launch(void* const* d_in, const int* in_sizes, int n_in,
                              void* d_out, int out_size, void* d_ws, size_t ws_size,
                              hipStream_t stream) {
    const float* x          = (const float*)d_in[0];
    const float* weight     = (const float*)d_in[1];
    const float* bias       = (const float*)d_in[2];
    const float* a_cache    = (const float*)d_in[3];
    const float* b_cache    = (const float*)d_in[4];
    const int*   b_start    = (const int*)d_in[5];
    const int*   b_adapter  = (const int*)d_in[6];
    const float* b_scaling  = (const float*)d_in[7];
    const int*   rpt        = (const int*)d_in[8];
    const int*   ranks      = (const int*)d_in[9];
    float* out = (float*)d_out;

    char* ws = (char*)d_ws;
    u16* xb = (u16*)ws; ws += (size_t)T_TOK * DIN * 2;          // 64 MiB
    u16* wb = (u16*)ws; ws += (size_t)DOUT * DIN * 2;           // 32 MiB
    u16* ab = (u16*)ws; ws += (size_t)CACHE_LEN * DIN * 2;      // 4 MiB
    u16* Bt = (u16*)ws; ws += (size_t)N_ADPT * DOUT * MAXR * 2; // 4 MiB
    u16* xa = (u16*)ws; ws += (size_t)T_TOK * MAXR * 2;         // 1 MiB

    cvt_kernel<<<2048, 256, 0, stream>>>(x, xb, T_TOK * DIN / 4);
    cvt_kernel<<<2048, 256, 0, stream>>>(weight, wb, DOUT * DIN / 4);
    cvt_kernel<<<512, 256, 0, stream>>>(a_cache, ab, CACHE_LEN * DIN / 4);
    build_bt<<<(N_ADPT * 8 * DOUT) / 256, 256, 0, stream>>>(b_cache, rpt, Bt);
    xa_kernel<<<T_TOK / 128, 256, 0, stream>>>(xb, ab, b_start, b_adapter, b_scaling, rpt, ranks, xa);
    gemm_kernel<<<(T_TOK / 128) * (DOUT / 128), 256, 0, stream>>>(xb, wb, bias, xa, Bt, b_start, b_adapter, out);
}

// Round 2
// 376.662 us; speedup vs baseline: 1.1973x; 1.1973x over previous
//
#include <hip/hip_runtime.h>
#include <hip/hip_bf16.h>

typedef unsigned short u16;
typedef unsigned int u32;
typedef __attribute__((ext_vector_type(8))) short bf16x8;
typedef __attribute__((ext_vector_type(4))) float f32x4;

#define T_TOK 8192
#define DIN 4096
#define DOUT 4096
#define N_SEQS 4
#define N_ADPT 8
#define MAXR 64
#define CACHE_LEN 512

__device__ __forceinline__ u16 f2bf(float f) {
    u32 u = __builtin_bit_cast(u32, f);
    u += 0x7fffu + ((u >> 16) & 1u);   // RNE
    return (u16)(u >> 16);
}

__device__ __forceinline__ void load_lds16(const u16* g, u16* l) {
    __builtin_amdgcn_global_load_lds(
        (const __attribute__((address_space(1))) u32*)g,
        (__attribute__((address_space(3))) u32*)l, 16, 0, 0);
}

// ---------------- fp32 -> bf16 convert (vectorized) ----------------
__global__ void cvt_kernel(const float* __restrict__ in, u16* __restrict__ out, int n4) {
    int i = blockIdx.x * blockDim.x + threadIdx.x;
    int stride = gridDim.x * blockDim.x;
    for (; i < n4; i += stride) {
        float4 v = reinterpret_cast<const float4*>(in)[i];
        ushort4 o;
        o.x = f2bf(v.x); o.y = f2bf(v.y); o.z = f2bf(v.z); o.w = f2bf(v.w);
        reinterpret_cast<ushort4*>(out)[i] = o;
    }
}

// ------------- build Bt[a][n][r] bf16 from b_cache via page table -------------
__global__ void build_bt(const float* __restrict__ b_cache, const int* __restrict__ rpt,
                         u16* __restrict__ Bt) {
    int id = blockIdx.x * 256 + threadIdx.x;      // total 8*8*4096 = 262144
    int n  = id & (DOUT - 1);
    int rb = (id >> 12) & 7;
    int a  = id >> 15;
    union { u16 u[8]; uint4 v; } pack;
    #pragma unroll
    for (int j = 0; j < 8; ++j) {
        int r = rb * 8 + j;
        int page = rpt[a * MAXR + r];
        pack.u[j] = f2bf(b_cache[(long)page * DOUT + n]);
    }
    *reinterpret_cast<uint4*>(&Bt[((long)(a * DOUT + n)) * MAXR + rb * 8]) = pack.v;
}

// ------------- xa[t][r] = scale * (x[t] . A[page(adapter,r)]), masked -------------
__launch_bounds__(256)
__global__ void xa_kernel(const u16* __restrict__ xb, const u16* __restrict__ ab,
                          const int* __restrict__ b_start_loc,
                          const int* __restrict__ b_adapter_ids,
                          const float* __restrict__ b_scaling,
                          const int* __restrict__ rpt,
                          const int* __restrict__ ranks,
                          u16* __restrict__ xa) {
    int t0 = blockIdx.x * 128;
    int seg = 0;
    #pragma unroll
    for (int i = 1; i < N_SEQS; ++i) if (b_start_loc[i] <= t0) seg = i;
    int adapter = b_adapter_ids[seg];
    float scale = b_scaling[seg];
    int rank = ranks[adapter];

    __shared__ __attribute__((aligned(16))) u16 As[128 * 32];
    __shared__ __attribute__((aligned(16))) u16 Bs[64 * 32];

    int tid = threadIdx.x;
    int lane = tid & 63, wave = tid >> 6;
    int lr = lane & 15, lk = lane >> 4;

    int e0 = wave * 64 + lane;               // [0,256)
    int e1 = 256 + e0;                       // [256,512)
    int ra0 = e0 >> 2, ca0 = (e0 & 3) * 8;
    int ra1 = e1 >> 2, ca1 = (e1 & 3) * 8;
    const u16* gA0 = xb + (long)(t0 + ra0) * DIN + ca0;
    const u16* gA1 = xb + (long)(t0 + ra1) * DIN + ca1;
    int rB = ra0;
    int page = rpt[adapter * MAXR + rB];
    const u16* gB = ab + (long)page * DIN + ca0;

    f32x4 acc[2][4] = {};

    for (int k0 = 0; k0 < DIN; k0 += 32) {
        load_lds16(gA0 + k0, As + wave * 512);
        load_lds16(gA1 + k0, As + 2048 + wave * 512);
        load_lds16(gB + k0,  Bs + wave * 512);
        asm volatile("s_waitcnt vmcnt(0)" ::: "memory");
        __syncthreads();
        bf16x8 af[2], bfr[4];
        #pragma unroll
        for (int m = 0; m < 2; ++m)
            af[m] = *(const bf16x8*)&As[(wave * 32 + m * 16 + lr) * 32 + lk * 8];
        #pragma unroll
        for (int n = 0; n < 4; ++n)
            bfr[n] = *(const bf16x8*)&Bs[(n * 16 + lr) * 32 + lk * 8];
        #pragma unroll
        for (int m = 0; m < 2; ++m)
            #pragma unroll
            for (int n = 0; n < 4; ++n)
                acc[m][n] = __builtin_amdgcn_mfma_f32_16x16x32_bf16(af[m], bfr[n], acc[m][n], 0, 0, 0);
        __syncthreads();
    }

    #pragma unroll
    for (int m = 0; m < 2; ++m) {
        int trow = t0 + wave * 32 + m * 16 + lk * 4;
        #pragma unroll
        for (int n = 0; n < 4; ++n) {
            int r = n * 16 + lr;
            #pragma unroll
            for (int j = 0; j < 4; ++j) {
                float v = (r < rank) ? acc[m][n][j] * scale : 0.0f;
                xa[(long)(trow + j) * MAXR + r] = f2bf(v);
            }
        }
    }
}

// ------------- main GEMM: 256x256 tile, BK=64, T1+T2+T4+T5, LoRA as K-tile 65 -------------
__launch_bounds__(512, 2)
__global__ void gemm256_kernel(const u16* __restrict__ xb, const u16* __restrict__ wb,
                               const float* __restrict__ bias,
                               const u16* __restrict__ xa, const u16* __restrict__ Bt,
                               const int* __restrict__ b_start_loc,
                               const int* __restrict__ b_adapter_ids,
                               float* __restrict__ out) {
    __shared__ __attribute__((aligned(16))) u16 lds[65536];   // A:2x16384, B:2x16384 (128 KiB)

    // T1: XCD-aware swizzle (nwg=512, 512%8==0 -> simple form is bijective)
    int bid = blockIdx.x;
    int wgid = (bid & 7) * 64 + (bid >> 3);
    int mt = wgid >> 4, nt = wgid & 15;
    int brow = mt * 256, bcol = nt * 256;

    int seg = 0;
    #pragma unroll
    for (int i = 1; i < N_SEQS; ++i) if (b_start_loc[i] <= brow) seg = i;
    int adapter = b_adapter_ids[seg];

    int tid = threadIdx.x;
    int lane = tid & 63, wave = tid >> 6;
    int wm = wave >> 2, wn = wave & 3;       // 2x4 wave grid, each 128x64 of C
    int lr = lane & 15, lk = lane >> 4;

    // ---- staging geometry (T2 both-sides swizzle; LDS dest linear) ----
    // physical chunk c = q*512 + tid covers LDS bytes c*16..c*16+15 of a 256x64 tile
    // physical (row = c>>3, pslot = tid&7); logical colslot = pslot ^ (row&7)
    int rb = tid >> 3;                        // row within 64-row group, invariant mod 8 across q
    int cs = (tid & 7) ^ (rb & 7);            // pre-swizzled source col slot
    const u16* aSrc  = xb + (long)(brow + rb) * DIN + cs * 8;
    const u16* wSrc  = wb + (long)(bcol + rb) * DIN + cs * 8;
    const u16* xaSrc = xa + (long)(brow + rb) * MAXR + cs * 8;
    const u16* btSrc = Bt + ((long)(adapter * DOUT + bcol + rb)) * MAXR + cs * 8;

    f32x4 acc[8][4] = {};

    #define STAGE(srcA, ldA, srcB, ldB, buf)                                        \
        do {                                                                        \
            u16* al = lds + (buf) * 16384 + wave * 512;                             \
            u16* bl = lds + 32768 + (buf) * 16384 + wave * 512;                     \
            _Pragma("unroll")                                                       \
            for (int q = 0; q < 4; ++q) {                                           \
                load_lds16((srcA) + (long)(q * 64) * (ldA), al + q * 4096);         \
                load_lds16((srcB) + (long)(q * 64) * (ldB), bl + q * 4096);         \
            }                                                                       \
        } while (0)

    STAGE(aSrc, DIN, wSrc, DIN, 0);           // prologue: tile 0 -> buf0

    for (int t = 0; t <= 64; ++t) {
        int cur = t & 1;
        if (t < 63) {
            STAGE(aSrc + (t + 1) * 64, DIN, wSrc + (t + 1) * 64, DIN, cur ^ 1);
            asm volatile("s_waitcnt vmcnt(8)" ::: "memory");   // T4: tile t landed, t+1 in flight
        } else if (t == 63) {
            STAGE(xaSrc, MAXR, btSrc, MAXR, cur ^ 1);          // LoRA K-tile
            asm volatile("s_waitcnt vmcnt(8)" ::: "memory");
        } else {
            asm volatile("s_waitcnt vmcnt(0)" ::: "memory");
        }
        __builtin_amdgcn_s_barrier();          // all waves: tile t data visible
        __builtin_amdgcn_sched_barrier(0);

        const u16* Ab = lds + cur * 16384;
        const u16* Bb = lds + 32768 + cur * 16384;

        #pragma unroll
        for (int q = 0; q < 4; ++q) {          // quadrants: (m-half, n-half)
            const int mh = q >> 1, nh = q & 1;
            bf16x8 af[4][2], bfr[2][2];
            #pragma unroll
            for (int mi = 0; mi < 4; ++mi) {
                int row = wm * 128 + (mh * 4 + mi) * 16 + lr;
                #pragma unroll
                for (int ks = 0; ks < 2; ++ks)
                    af[mi][ks] = *(const bf16x8*)&Ab[row * 64 + (((ks * 4 + lk) ^ (lr & 7)) * 8)];
            }
            #pragma unroll
            for (int ni = 0; ni < 2; ++ni) {
                int row = wn * 64 + (nh * 2 + ni) * 16 + lr;
                #pragma unroll
                for (int ks = 0; ks < 2; ++ks)
                    bfr[ni][ks] = *(const bf16x8*)&Bb[row * 64 + (((ks * 4 + lk) ^ (lr & 7)) * 8)];
            }
            __builtin_amdgcn_s_setprio(1);     // T5
            #pragma unroll
            for (int ks = 0; ks < 2; ++ks)
                #pragma unroll
                for (int mi = 0; mi < 4; ++mi)
                    #pragma unroll
                    for (int ni = 0; ni < 2; ++ni)
                        acc[mh * 4 + mi][nh * 2 + ni] = __builtin_amdgcn_mfma_f32_16x16x32_bf16(
                            af[mi][ks], bfr[ni][ks], acc[mh * 4 + mi][nh * 2 + ni], 0, 0, 0);
            __builtin_amdgcn_s_setprio(0);
        }

        if (t < 64) {
            __builtin_amdgcn_s_barrier();      // all waves done reading buf[cur] before overwrite
            __builtin_amdgcn_sched_barrier(0);
        }
    }
    #undef STAGE

    // ---- epilogue: + bias, fp32 store ----
    #pragma unroll
    for (int m = 0; m < 8; ++m) {
        int orow = brow + wm * 128 + m * 16 + lk * 4;
        #pragma unroll
        for (int n = 0; n < 4; ++n) {
            int ocol = bcol + wn * 64 + n * 16 + lr;
            float bv = bias[ocol];
            #pragma unroll
            for (int j = 0; j < 4; ++j)
                out[(long)(orow + j) * DOUT + ocol] = acc[m][n][j] + bv;
        }
    }
}

extern "C" void kernel_launch(void* const* d_in, const int* in_sizes, int n_in,
                              void* d_out, int out_size, void* d_ws, size_t ws_size,
                              hipStream_t stream) {
    const float* x          = (const float*)d_in[0];
    const float* weight     = (const float*)d_in[1];
    const float* bias       = (const float*)d_in[2];
    const float* a_cache    = (const float*)d_in[3];
    const float* b_cache    = (const float*)d_in[4];
    const int*   b_start    = (const int*)d_in[5];
    const int*   b_adapter  = (const int*)d_in[6];
    const float* b_scaling  = (const float*)d_in[7];
    const int*   rpt        = (const int*)d_in[8];
    const int*   ranks      = (const int*)d_in[9];
    float* out = (float*)d_out;

    char* ws = (char*)d_ws;
    u16* xb = (u16*)ws; ws += (size_t)T_TOK * DIN * 2;          // 64 MiB
    u16* wb = (u16*)ws; ws += (size_t)DOUT * DIN * 2;           // 32 MiB
    u16* ab = (u16*)ws; ws += (size_t)CACHE_LEN * DIN * 2;      // 4 MiB
    u16* Bt = (u16*)ws; ws += (size_t)N_ADPT * DOUT * MAXR * 2; // 4 MiB
    u16* xa = (u16*)ws; ws += (size_t)T_TOK * MAXR * 2;         // 1 MiB

    cvt_kernel<<<2048, 256, 0, stream>>>(x, xb, T_TOK * DIN / 4);
    cvt_kernel<<<2048, 256, 0, stream>>>(weight, wb, DOUT * DIN / 4);
    cvt_kernel<<<512, 256, 0, stream>>>(a_cache, ab, CACHE_LEN * DIN / 4);
    build_bt<<<(N_ADPT * 8 * DOUT) / 256, 256, 0, stream>>>(b_cache, rpt, Bt);
    xa_kernel<<<T_TOK / 128, 256, 0, stream>>>(xb, ab, b_start, b_adapter, b_scaling, rpt, ranks, xa);
    gemm256_kernel<<<(T_TOK / 256) * (DOUT / 256), 512, 0, stream>>>(xb, wb, bias, xa, Bt, b_start, b_adapter, out);
}

// Round 4
// 369.371 us; speedup vs baseline: 1.2209x; 1.0197x over previous
//
#include <hip/hip_runtime.h>
#include <hip/hip_bf16.h>

typedef unsigned short u16;
typedef unsigned int u32;
typedef __attribute__((ext_vector_type(8))) short bf16x8;
typedef __attribute__((ext_vector_type(4))) float f32x4;

#define T_TOK 8192
#define DIN 4096
#define DOUT 4096
#define N_SEQS 4
#define N_ADPT 8
#define MAXR 64
#define CACHE_LEN 512

__device__ __forceinline__ u16 f2bf(float f) {
    u32 u = __builtin_bit_cast(u32, f);
    u += 0x7fffu + ((u >> 16) & 1u);   // RNE
    return (u16)(u >> 16);
}

__device__ __forceinline__ void load_lds16(const u16* g, u16* l) {
    __builtin_amdgcn_global_load_lds(
        (const __attribute__((address_space(1))) u32*)g,
        (__attribute__((address_space(3))) u32*)l, 16, 0, 0);
}

// ---------------- fp32 -> bf16 convert (vectorized) ----------------
__global__ void cvt_kernel(const float* __restrict__ in, u16* __restrict__ out, int n4) {
    int i = blockIdx.x * blockDim.x + threadIdx.x;
    int stride = gridDim.x * blockDim.x;
    for (; i < n4; i += stride) {
        float4 v = reinterpret_cast<const float4*>(in)[i];
        ushort4 o;
        o.x = f2bf(v.x); o.y = f2bf(v.y); o.z = f2bf(v.z); o.w = f2bf(v.w);
        reinterpret_cast<ushort4*>(out)[i] = o;
    }
}

// ------------- build Bt[a][n][r] bf16 from b_cache via page table -------------
__global__ void build_bt(const float* __restrict__ b_cache, const int* __restrict__ rpt,
                         u16* __restrict__ Bt) {
    int id = blockIdx.x * 256 + threadIdx.x;      // total 8*8*4096 = 262144
    int n  = id & (DOUT - 1);
    int rb = (id >> 12) & 7;
    int a  = id >> 15;
    union { u16 u[8]; uint4 v; } pack;
    #pragma unroll
    for (int j = 0; j < 8; ++j) {
        int r = rb * 8 + j;
        int page = rpt[a * MAXR + r];
        pack.u[j] = f2bf(b_cache[(long)page * DOUT + n]);
    }
    *reinterpret_cast<uint4*>(&Bt[((long)(a * DOUT + n)) * MAXR + rb * 8]) = pack.v;
}

// ------------- xa[t][r] = scale * (x[t] . A[page(adapter,r)]), masked -------------
__launch_bounds__(256)
__global__ void xa_kernel(const u16* __restrict__ xb, const u16* __restrict__ ab,
                          const int* __restrict__ b_start_loc,
                          const int* __restrict__ b_adapter_ids,
                          const float* __restrict__ b_scaling,
                          const int* __restrict__ rpt,
                          const int* __restrict__ ranks,
                          u16* __restrict__ xa) {
    int t0 = blockIdx.x * 128;
    int seg = 0;
    #pragma unroll
    for (int i = 1; i < N_SEQS; ++i) if (b_start_loc[i] <= t0) seg = i;
    int adapter = b_adapter_ids[seg];
    float scale = b_scaling[seg];
    int rank = ranks[adapter];

    __shared__ __attribute__((aligned(16))) u16 As[128 * 32];
    __shared__ __attribute__((aligned(16))) u16 Bs[64 * 32];

    int tid = threadIdx.x;
    int lane = tid & 63, wave = tid >> 6;
    int lr = lane & 15, lk = lane >> 4;

    int e0 = wave * 64 + lane;               // [0,256)
    int e1 = 256 + e0;                       // [256,512)
    int ra0 = e0 >> 2, ca0 = (e0 & 3) * 8;
    int ra1 = e1 >> 2, ca1 = (e1 & 3) * 8;
    const u16* gA0 = xb + (long)(t0 + ra0) * DIN + ca0;
    const u16* gA1 = xb + (long)(t0 + ra1) * DIN + ca1;
    int rB = ra0;
    int page = rpt[adapter * MAXR + rB];
    const u16* gB = ab + (long)page * DIN + ca0;

    f32x4 acc[2][4] = {};

    for (int k0 = 0; k0 < DIN; k0 += 32) {
        load_lds16(gA0 + k0, As + wave * 512);
        load_lds16(gA1 + k0, As + 2048 + wave * 512);
        load_lds16(gB + k0,  Bs + wave * 512);
        asm volatile("s_waitcnt vmcnt(0)" ::: "memory");
        __syncthreads();
        bf16x8 af[2], bfr[4];
        #pragma unroll
        for (int m = 0; m < 2; ++m)
            af[m] = *(const bf16x8*)&As[(wave * 32 + m * 16 + lr) * 32 + lk * 8];
        #pragma unroll
        for (int n = 0; n < 4; ++n)
            bfr[n] = *(const bf16x8*)&Bs[(n * 16 + lr) * 32 + lk * 8];
        #pragma unroll
        for (int m = 0; m < 2; ++m)
            #pragma unroll
            for (int n = 0; n < 4; ++n)
                acc[m][n] = __builtin_amdgcn_mfma_f32_16x16x32_bf16(af[m], bfr[n], acc[m][n], 0, 0, 0);
        __syncthreads();
    }

    #pragma unroll
    for (int m = 0; m < 2; ++m) {
        int trow = t0 + wave * 32 + m * 16 + lk * 4;
        #pragma unroll
        for (int n = 0; n < 4; ++n) {
            int r = n * 16 + lr;
            #pragma unroll
            for (int j = 0; j < 4; ++j) {
                float v = (r < rank) ? acc[m][n][j] * scale : 0.0f;
                xa[(long)(trow + j) * MAXR + r] = f2bf(v);
            }
        }
    }
}

// ------------- main GEMM: 256x256 tile, BK=64, T1+T2+T4+T5, LoRA as K-tile 65 -------------
// Schedule = R1's proven order: STAGE(t+1) -> vmcnt(8) -> barrier -> compute -> barrier.
// Compute = R2's fragment residency: B resident per K-tile, A once per m-half
// (24 ds_read_b128/tile/wave instead of 48).
__launch_bounds__(512, 2)
__global__ void gemm256_kernel(const u16* __restrict__ xb, const u16* __restrict__ wb,
                               const float* __restrict__ bias,
                               const u16* __restrict__ xa, const u16* __restrict__ Bt,
                               const int* __restrict__ b_start_loc,
                               const int* __restrict__ b_adapter_ids,
                               float* __restrict__ out) {
    __shared__ __attribute__((aligned(16))) u16 lds[65536];   // A:2x16384, B:2x16384 (128 KiB)

    // T1: XCD-aware swizzle (nwg=512, 512%8==0 -> simple form is bijective)
    int bid = blockIdx.x;
    int wgid = (bid & 7) * 64 + (bid >> 3);
    int mt = wgid >> 4, nt = wgid & 15;
    int brow = mt * 256, bcol = nt * 256;

    int seg = 0;
    #pragma unroll
    for (int i = 1; i < N_SEQS; ++i) if (b_start_loc[i] <= brow) seg = i;
    int adapter = b_adapter_ids[seg];

    int tid = threadIdx.x;
    int lane = tid & 63, wave = tid >> 6;
    int wm = wave >> 2, wn = wave & 3;       // 2x4 wave grid, each 128x64 of C
    int lr = lane & 15, lk = lane >> 4;

    // ---- staging geometry (T2 both-sides swizzle; LDS dest linear) ----
    int rb = tid >> 3;                        // row within 64-row group, invariant mod 8 across q
    int cs = (tid & 7) ^ (rb & 7);            // pre-swizzled source col slot
    const u16* aSrc  = xb + (long)(brow + rb) * DIN + cs * 8;
    const u16* wSrc  = wb + (long)(bcol + rb) * DIN + cs * 8;
    const u16* xaSrc = xa + (long)(brow + rb) * MAXR + cs * 8;
    const u16* btSrc = Bt + ((long)(adapter * DOUT + bcol + rb)) * MAXR + cs * 8;

    f32x4 acc[8][4] = {};

    #define STAGE(srcA, ldA, srcB, ldB, buf)                                        \
        do {                                                                        \
            u16* al = lds + (buf) * 16384 + wave * 512;                             \
            u16* bl = lds + 32768 + (buf) * 16384 + wave * 512;                     \
            _Pragma("unroll")                                                       \
            for (int q = 0; q < 4; ++q) {                                           \
                load_lds16((srcA) + (long)(q * 64) * (ldA), al + q * 4096);         \
                load_lds16((srcB) + (long)(q * 64) * (ldB), bl + q * 4096);         \
            }                                                                       \
        } while (0)

    STAGE(aSrc, DIN, wSrc, DIN, 0);           // prologue: tile 0 -> buf0

    for (int t = 0; t <= 64; ++t) {
        int cur = t & 1;
        if (t < 63) {
            // issue tile t+1 FIRST, then vmcnt(8) == "tile t's 8 loads landed,
            // tile t+1's 8 still in flight" (T4 counted-wait)
            STAGE(aSrc + (t + 1) * 64, DIN, wSrc + (t + 1) * 64, DIN, cur ^ 1);
            asm volatile("s_waitcnt vmcnt(8)" ::: "memory");
        } else if (t == 63) {
            STAGE(xaSrc, MAXR, btSrc, MAXR, cur ^ 1);          // LoRA K-tile
            asm volatile("s_waitcnt vmcnt(8)" ::: "memory");
        } else {
            asm volatile("s_waitcnt vmcnt(0)" ::: "memory");
        }
        __builtin_amdgcn_s_barrier();          // all waves: tile t data visible
        __builtin_amdgcn_sched_barrier(0);

        const u16* Ab = lds + cur * 16384;
        const u16* Bb = lds + 32768 + cur * 16384;

        // B fragments resident for the whole K-tile (8 reads)
        bf16x8 bfr[4][2];
        #pragma unroll
        for (int ni = 0; ni < 4; ++ni) {
            int row = wn * 64 + ni * 16 + lr;
            #pragma unroll
            for (int ks = 0; ks < 2; ++ks)
                bfr[ni][ks] = *(const bf16x8*)&Bb[row * 64 + (((ks * 4 + lk) ^ (lr & 7)) * 8)];
        }
        // A fragments once per m-half (8 reads each), 32 MFMA per half
        #pragma unroll
        for (int mh = 0; mh < 2; ++mh) {
            bf16x8 af[4][2];
            #pragma unroll
            for (int mi = 0; mi < 4; ++mi) {
                int row = wm * 128 + (mh * 4 + mi) * 16 + lr;
                #pragma unroll
                for (int ks = 0; ks < 2; ++ks)
                    af[mi][ks] = *(const bf16x8*)&Ab[row * 64 + (((ks * 4 + lk) ^ (lr & 7)) * 8)];
            }
            __builtin_amdgcn_s_setprio(1);     // T5
            #pragma unroll
            for (int ks = 0; ks < 2; ++ks)
                #pragma unroll
                for (int mi = 0; mi < 4; ++mi)
                    #pragma unroll
                    for (int ni = 0; ni < 4; ++ni)
                        acc[mh * 4 + mi][ni] = __builtin_amdgcn_mfma_f32_16x16x32_bf16(
                            af[mi][ks], bfr[ni][ks], acc[mh * 4 + mi][ni], 0, 0, 0);
            __builtin_amdgcn_s_setprio(0);
        }

        if (t < 64) {
            __builtin_amdgcn_s_barrier();      // all waves done reading buf[cur] before overwrite
            __builtin_amdgcn_sched_barrier(0);
        }
    }
    #undef STAGE

    // ---- epilogue: + bias, fp32 store ----
    #pragma unroll
    for (int m = 0; m < 8; ++m) {
        int orow = brow + wm * 128 + m * 16 + lk * 4;
        #pragma unroll
        for (int n = 0; n < 4; ++n) {
            int ocol = bcol + wn * 64 + n * 16 + lr;
            float bv = bias[ocol];
            #pragma unroll
            for (int j = 0; j < 4; ++j)
                out[(long)(orow + j) * DOUT + ocol] = acc[m][n][j] + bv;
        }
    }
}

extern "C" void kernel_launch(void* const* d_in, const int* in_sizes, int n_in,
                              void* d_out, int out_size, void* d_ws, size_t ws_size,
                              hipStream_t stream) {
    const float* x          = (const float*)d_in[0];
    const float* weight     = (const float*)d_in[1];
    const float* bias       = (const float*)d_in[2];
    const float* a_cache    = (const float*)d_in[3];
    const float* b_cache    = (const float*)d_in[4];
    const int*   b_start    = (const int*)d_in[5];
    const int*   b_adapter  = (const int*)d_in[6];
    const float* b_scaling  = (const float*)d_in[7];
    const int*   rpt        = (const int*)d_in[8];
    const int*   ranks      = (const int*)d_in[9];
    float* out = (float*)d_out;

    char* ws = (char*)d_ws;
    u16* xb = (u16*)ws; ws += (size_t)T_TOK * DIN * 2;          // 64 MiB
    u16* wb = (u16*)ws; ws += (size_t)DOUT * DIN * 2;           // 32 MiB
    u16* ab = (u16*)ws; ws += (size_t)CACHE_LEN * DIN * 2;      // 4 MiB
    u16* Bt = (u16*)ws; ws += (size_t)N_ADPT * DOUT * MAXR * 2; // 4 MiB
    u16* xa = (u16*)ws; ws += (size_t)T_TOK * MAXR * 2;         // 1 MiB

    cvt_kernel<<<2048, 256, 0, stream>>>(x, xb, T_TOK * DIN / 4);
    cvt_kernel<<<2048, 256, 0, stream>>>(weight, wb, DOUT * DIN / 4);
    cvt_kernel<<<512, 256, 0, stream>>>(a_cache, ab, CACHE_LEN * DIN / 4);
    build_bt<<<(N_ADPT * 8 * DOUT) / 256, 256, 0, stream>>>(b_cache, rpt, Bt);
    xa_kernel<<<T_TOK / 128, 256, 0, stream>>>(xb, ab, b_start, b_adapter, b_scaling, rpt, ranks, xa);
    gemm256_kernel<<<(T_TOK / 256) * (DOUT / 256), 512, 0, stream>>>(xb, wb, bias, xa, Bt, b_start, b_adapter, out);
}